// Round 6
// baseline (92.258 us; speedup 1.0000x reference)
//
#include <hip/hip_runtime.h>
#include <math.h>

// Problem constants (B=2, H=W=64, K=4, GDIM=9)
#define NPIX 4096           // H*W
#define BATCH 2
#define TWO_PI 6.28318530717958647692f
#define LOG2E 1.44269504088896340736f

// Fused render geometry: block = (b, ptile of 32 pixels), 512 threads (8 waves).
// lane = seg(0..31) | slot(bit5); each thread integrates a 128-Gaussian segment
// for TWO same-row adjacent pixels (halves LDS traffic, shares dy terms).
#define RSEG 32
#define RSEGLEN 128         // NPIX / RSEG
#define SEG_STRIDE4 257     // float4 stride per segment: 128*2 + 1 (16B pad)

__device__ __forceinline__ float sigmoidf_(float x) {
    return 1.0f / (1.0f + __expf(-x));
}
// tanh via exp: 1 - 2/(e^{2x}+1). Saturates correctly at +/-1.
__device__ __forceinline__ float tanhf_(float x) {
    return 1.0f - 2.0f / (__expf(2.0f * x) + 1.0f);
}

// ---------------------------------------------------------------------------
// Kernel 1: per-(pixel,k) Gaussian parameters; conv(3->64)+head(64->36) weights
// folded per-block into LDS. 4 lanes per pixel (k = tid&3); softmax + weighted
// sums via 4-lane shfl_xor. Conic pre-scaled by -0.5*log2e so render is exp2:
// params4[pix*2+0] = {m0, m1, na, nb} ; params4[pix*2+1] = {nc, r, g, b}
// ---------------------------------------------------------------------------
__global__ __launch_bounds__(256) void params_kernel(
        const float* __restrict__ inp,     // (2,3,64,64)
        const float* __restrict__ enc_w,   // (64,3,3,3)
        const float* __restrict__ enc_b,   // (64,)
        const float* __restrict__ head_w,  // (36,64)
        const float* __restrict__ head_b,  // (36,)
        float4* __restrict__ params4) {
    __shared__ float cw[1008];  // [0,972): comb_w[o*27+j], [972,1008): comb_b[o]
    int t = threadIdx.x;
    #pragma unroll
    for (int i = 0; i < 4; ++i) {
        int e = t + i * 256;
        if (e < 972) {
            int o = e / 27, j = e % 27;
            float s = 0.0f;
            #pragma unroll 8
            for (int c = 0; c < 64; ++c)
                s = fmaf(head_w[o * 64 + c], enc_w[c * 27 + j], s);
            cw[e] = s;
        } else if (e < 1008) {
            int o = e - 972;
            float s = head_b[o];
            #pragma unroll 8
            for (int c = 0; c < 64; ++c)
                s = fmaf(head_w[o * 64 + c], enc_b[c], s);
            cw[e] = s;
        }
    }
    __syncthreads();

    int gid = blockIdx.x * 256 + t;      // 0..32767
    int k   = gid & 3;
    int pix = gid >> 2;                  // 0..8191
    int b = pix >> 12;
    int n = pix & 4095;
    int h = n >> 6, w = n & 63;

    // 3x3x3 neighborhood, zero-padded (SAME)
    float x[27];
    const float* base = inp + b * 3 * NPIX;
    #pragma unroll
    for (int ci = 0; ci < 3; ++ci) {
        #pragma unroll
        for (int dh = -1; dh <= 1; ++dh) {
            #pragma unroll
            for (int dw = -1; dw <= 1; ++dw) {
                int hh = h + dh, ww = w + dw;
                float v = 0.0f;
                if (hh >= 0 && hh < 64 && ww >= 0 && ww < 64)
                    v = base[ci * NPIX + hh * 64 + ww];
                x[ci * 9 + (dh + 1) * 3 + (dw + 1)] = v;
            }
        }
    }

    // 9 channels for this k
    const int ob = k * 9;
    float pr[9];
    #pragma unroll
    for (int j = 0; j < 9; ++j) {
        float s = cw[972 + ob + j];
        #pragma unroll
        for (int q = 0; q < 27; ++q)
            s = fmaf(x[q], cw[(ob + j) * 27 + q], s);
        pr[j] = s;
    }

    // softmax over the 4-lane group (lane layout: pix*4 + k)
    float wl = pr[8];
    float mx = fmaxf(wl, __shfl_xor(wl, 1));
    mx = fmaxf(mx, __shfl_xor(mx, 2));
    float e = __expf(wl - mx);
    float se = e + __shfl_xor(e, 1);
    se += __shfl_xor(se, 2);
    float wk = e / se;

    // this-k weighted contributions
    float r  = wk * pr[0];
    float g  = wk * pr[1];
    float bl = wk * pr[2];
    float th = wk * (sigmoidf_(pr[3]) * TWO_PI);
    float s0 = wk * (sigmoidf_(pr[4]) * 0.5f + 1e-6f);
    float s1 = wk * (sigmoidf_(pr[5]) * 0.5f + 1e-6f);
    float o0 = wk * tanhf_(pr[6]);
    float o1 = wk * tanhf_(pr[7]);

    // sum across the 4-lane group
    #define GSUM2(v) { v += __shfl_xor(v, 1); v += __shfl_xor(v, 2); }
    GSUM2(r) GSUM2(g) GSUM2(bl) GSUM2(th) GSUM2(s0) GSUM2(s1) GSUM2(o0) GSUM2(o1)
    #undef GSUM2

    if (k == 0) {
        float isx = 1.0f / (s0 * s0);
        float isy = 1.0f / (s1 * s1);
        float c_, s_;
        __sincosf(th, &s_, &c_);
        float ca = c_ * c_ * isx + s_ * s_ * isy;
        float cb = c_ * s_ * (isx - isy);
        float cc = s_ * s_ * isx + c_ * c_ * isy;

        float coord0 = (float)(n & 63) * 0.03125f - 1.0f;   // 2*w/W - 1
        float coord1 = (float)(n >> 6) * 0.03125f - 1.0f;   // 2*h/H - 1
        float m0 = coord0 + o0 * 0.03125f - 0.015625f;      // + 2*off/W - 1/W
        float m1 = coord1 + o1 * 0.03125f - 0.015625f;

        float na = -(0.5f * LOG2E) * ca;
        float nb = -LOG2E * cb;
        float nc = -(0.5f * LOG2E) * cc;

        params4[pix * 2 + 0] = make_float4(m0, m1, na, nb);
        params4[pix * 2 + 1] = make_float4(nc, r, g, bl);
    }
}

// ---------------------------------------------------------------------------
// Kernel 2: fused render + reduce. Block = (b, ptile of 32 pixels), 512 thr.
// All 4096 Gaussians of batch b staged in LDS (padded: float4 stride 257/seg).
// Thread = (seg, slot): integrates its 128-Gaussian segment for 2 adjacent
// same-row pixels (pixpair = wave*4 + slot*2). dy-terms shared across the
// pixel pair. 5-step shfl_xor reduce over seg lanes; seg==0 writes both px.
// tt_i = dx_i*(na*dx_i + nb*dy) + nc*dy^2 ; alpha = exp2(tt) gated on tt<=0.
// ---------------------------------------------------------------------------
__global__ __launch_bounds__(512) void render_kernel(
        const float4* __restrict__ params4,
        float* __restrict__ out) {
    extern __shared__ float4 lp[];   // 32 segs * 257 float4 = 131584 B
    int t = threadIdx.x;
    int bi = blockIdx.x;
    int ptile = bi & 127;            // 32-pixel tile
    int b     = bi >> 7;

    // stage: 8192 float4s; dest addr = 4*idx + seg*4 dwords -> linear per seg,
    // consecutive threads write consecutive 16B chunks (conflict-free).
    const float4* src = params4 + b * (NPIX * 2);
    #pragma unroll
    for (int i = 0; i < 16; ++i) {
        int idx  = t + i * 512;      // 0..8191
        int nn   = idx >> 1;
        int half = idx & 1;
        int seg  = nn >> 7;
        int j    = nn & 127;
        lp[seg * SEG_STRIDE4 + j * 2 + half] = src[idx];
    }
    __syncthreads();

    int lane = t & 63;
    int wave = t >> 6;               // 0..7
    int seg  = lane & 31;
    int slot = lane >> 5;            // 0..1
    int pixpair = wave * 4 + slot * 2;        // 0,2,..,30
    int p0 = ptile * 32 + pixpair;            // even column index
    int p1 = p0 + 1;

    float px0 = (float)(p0 & 63) * 0.03125f - 1.0f;
    float px1 = px0 + 0.03125f;
    float py  = (float)(p0 >> 6) * 0.03125f - 1.0f;

    const float4* seg_base = lp + seg * SEG_STRIDE4;
    float ar0 = 0.f, ag0 = 0.f, ab0 = 0.f;
    float ar1 = 0.f, ag1 = 0.f, ab1 = 0.f;
    #pragma unroll 8
    for (int j = 0; j < RSEGLEN; ++j) {
        float4 q0 = seg_base[2 * j];   // {m0, m1, na, nb}
        float4 q1 = seg_base[2 * j + 1]; // {nc, r, g, b}
        float dy = py - q0.y;
        float v  = q0.w * dy;          // nb*dy (shared)
        float u  = (q1.x * dy) * dy;   // nc*dy^2 (shared)
        float dx0 = px0 - q0.x;
        float dx1 = dx0 + 0.03125f;
        float tt0 = fmaf(dx0, fmaf(q0.z, dx0, v), u);
        float tt1 = fmaf(dx1, fmaf(q0.z, dx1, v), u);
        float a0 = (tt0 <= 0.0f) ? __builtin_amdgcn_exp2f(tt0) : 0.0f;
        float a1 = (tt1 <= 0.0f) ? __builtin_amdgcn_exp2f(tt1) : 0.0f;
        ar0 = fmaf(a0, q1.y, ar0);
        ag0 = fmaf(a0, q1.z, ag0);
        ab0 = fmaf(a0, q1.w, ab0);
        ar1 = fmaf(a1, q1.y, ar1);
        ag1 = fmaf(a1, q1.z, ag1);
        ab1 = fmaf(a1, q1.w, ab1);
    }

    // reduce over the 32 seg-lanes (slot bit 5 preserved by xor<32)
    #define GSUM(v) { v += __shfl_xor(v, 1); v += __shfl_xor(v, 2); \
                      v += __shfl_xor(v, 4); v += __shfl_xor(v, 8); \
                      v += __shfl_xor(v, 16); }
    GSUM(ar0) GSUM(ag0) GSUM(ab0) GSUM(ar1) GSUM(ag1) GSUM(ab1)
    #undef GSUM

    if (seg == 0) {
        ar0 = fminf(fmaxf(ar0, 0.0f), 1.0f);
        ag0 = fminf(fmaxf(ag0, 0.0f), 1.0f);
        ab0 = fminf(fmaxf(ab0, 0.0f), 1.0f);
        ar1 = fminf(fmaxf(ar1, 0.0f), 1.0f);
        ag1 = fminf(fmaxf(ag1, 0.0f), 1.0f);
        ab1 = fminf(fmaxf(ab1, 0.0f), 1.0f);
        out[(b * 3 + 0) * NPIX + p0] = ar0;
        out[(b * 3 + 1) * NPIX + p0] = ag0;
        out[(b * 3 + 2) * NPIX + p0] = ab0;
        out[(b * 3 + 0) * NPIX + p1] = ar1;
        out[(b * 3 + 1) * NPIX + p1] = ag1;
        out[(b * 3 + 2) * NPIX + p1] = ab1;
    }
}

// ---------------------------------------------------------------------------
extern "C" void kernel_launch(void* const* d_in, const int* in_sizes, int n_in,
                              void* d_out, int out_size, void* d_ws, size_t ws_size,
                              hipStream_t stream) {
    const float* inp    = (const float*)d_in[0];  // (2,3,64,64)
    const float* enc_w  = (const float*)d_in[1];  // (64,3,3,3)
    const float* enc_b  = (const float*)d_in[2];  // (64,)
    const float* head_w = (const float*)d_in[3];  // (36,64)
    const float* head_b = (const float*)d_in[4];  // (36,)
    float* out = (float*)d_out;                   // (2,3,64,64)

    float4* params4 = (float4*)d_ws;              // BN*2 float4 = 256 KB

    params_kernel<<<128, 256, 0, stream>>>(inp, enc_w, enc_b,
                                           head_w, head_b, params4);
    size_t shmem = (size_t)RSEG * SEG_STRIDE4 * sizeof(float4);  // 131584 B
    render_kernel<<<BATCH * (NPIX / 32), 512, shmem, stream>>>(params4, out);
}

// Round 8
// 89.969 us; speedup vs baseline: 1.0254x; 1.0254x over previous
//
#include <hip/hip_runtime.h>
#include <math.h>

// Problem constants (B=2, H=W=64, K=4, GDIM=9)
#define NPIX 4096           // H*W
#define BATCH 2
#define TWO_PI 6.28318530717958647692f
#define LOG2E 1.44269504088896340736f

// Render geometry: block = (b, ptile of 32 pixels), 1024 threads (16 waves).
// wave = one pixel-pair (2 adjacent same-row pixels); lane l integrates
// Gaussians [l*64, l*64+64) for both pixels; full-wave butterfly reduce.
#define RSEG 64
#define RSEGLEN 64          // NPIX / RSEG
#define SEG_STRIDE4 129     // float4 stride per segment: 64*2 + 1 (16B pad)

__device__ __forceinline__ float sigmoidf_(float x) {
    return 1.0f / (1.0f + __expf(-x));
}
// tanh via exp: 1 - 2/(e^{2x}+1). Saturates correctly at +/-1.
__device__ __forceinline__ float tanhf_(float x) {
    return 1.0f - 2.0f / (__expf(2.0f * x) + 1.0f);
}

// ---------------------------------------------------------------------------
// Kernel 1: per-(pixel,k) Gaussian parameters; conv(3->64)+head(64->36) weights
// folded per-block into LDS. 4 lanes per pixel (k = tid&3); softmax + weighted
// sums via 4-lane shfl_xor. Conic pre-scaled by -0.5*log2e so render is exp2:
// params4[pix*2+0] = {m0, m1, na, nb} ; params4[pix*2+1] = {nc, r, g, b}
// ---------------------------------------------------------------------------
__global__ __launch_bounds__(256) void params_kernel(
        const float* __restrict__ inp,     // (2,3,64,64)
        const float* __restrict__ enc_w,   // (64,3,3,3)
        const float* __restrict__ enc_b,   // (64,)
        const float* __restrict__ head_w,  // (36,64)
        const float* __restrict__ head_b,  // (36,)
        float4* __restrict__ params4) {
    __shared__ float cw[1008];  // [0,972): comb_w[o*27+j], [972,1008): comb_b[o]
    int t = threadIdx.x;
    #pragma unroll
    for (int i = 0; i < 4; ++i) {
        int e = t + i * 256;
        if (e < 972) {
            int o = e / 27, j = e % 27;
            float s = 0.0f;
            #pragma unroll 8
            for (int c = 0; c < 64; ++c)
                s = fmaf(head_w[o * 64 + c], enc_w[c * 27 + j], s);
            cw[e] = s;
        } else if (e < 1008) {
            int o = e - 972;
            float s = head_b[o];
            #pragma unroll 8
            for (int c = 0; c < 64; ++c)
                s = fmaf(head_w[o * 64 + c], enc_b[c], s);
            cw[e] = s;
        }
    }
    __syncthreads();

    int gid = blockIdx.x * 256 + t;      // 0..32767
    int k   = gid & 3;
    int pix = gid >> 2;                  // 0..8191
    int b = pix >> 12;
    int n = pix & 4095;
    int h = n >> 6, w = n & 63;

    // 3x3x3 neighborhood, zero-padded (SAME)
    float x[27];
    const float* base = inp + b * 3 * NPIX;
    #pragma unroll
    for (int ci = 0; ci < 3; ++ci) {
        #pragma unroll
        for (int dh = -1; dh <= 1; ++dh) {
            #pragma unroll
            for (int dw = -1; dw <= 1; ++dw) {
                int hh = h + dh, ww = w + dw;
                float v = 0.0f;
                if (hh >= 0 && hh < 64 && ww >= 0 && ww < 64)
                    v = base[ci * NPIX + hh * 64 + ww];
                x[ci * 9 + (dh + 1) * 3 + (dw + 1)] = v;
            }
        }
    }

    // 9 channels for this k
    const int ob = k * 9;
    float pr[9];
    #pragma unroll
    for (int j = 0; j < 9; ++j) {
        float s = cw[972 + ob + j];
        #pragma unroll
        for (int q = 0; q < 27; ++q)
            s = fmaf(x[q], cw[(ob + j) * 27 + q], s);
        pr[j] = s;
    }

    // softmax over the 4-lane group (lane layout: pix*4 + k)
    float wl = pr[8];
    float mx = fmaxf(wl, __shfl_xor(wl, 1));
    mx = fmaxf(mx, __shfl_xor(mx, 2));
    float e = __expf(wl - mx);
    float se = e + __shfl_xor(e, 1);
    se += __shfl_xor(se, 2);
    float wk = e / se;

    // this-k weighted contributions
    float r  = wk * pr[0];
    float g  = wk * pr[1];
    float bl = wk * pr[2];
    float th = wk * (sigmoidf_(pr[3]) * TWO_PI);
    float s0 = wk * (sigmoidf_(pr[4]) * 0.5f + 1e-6f);
    float s1 = wk * (sigmoidf_(pr[5]) * 0.5f + 1e-6f);
    float o0 = wk * tanhf_(pr[6]);
    float o1 = wk * tanhf_(pr[7]);

    // sum across the 4-lane group
    #define GSUM2(v) { v += __shfl_xor(v, 1); v += __shfl_xor(v, 2); }
    GSUM2(r) GSUM2(g) GSUM2(bl) GSUM2(th) GSUM2(s0) GSUM2(s1) GSUM2(o0) GSUM2(o1)
    #undef GSUM2

    if (k == 0) {
        float isx = 1.0f / (s0 * s0);
        float isy = 1.0f / (s1 * s1);
        float c_, s_;
        __sincosf(th, &s_, &c_);
        float ca = c_ * c_ * isx + s_ * s_ * isy;
        float cb = c_ * s_ * (isx - isy);
        float cc = s_ * s_ * isx + c_ * c_ * isy;

        float coord0 = (float)(n & 63) * 0.03125f - 1.0f;   // 2*w/W - 1
        float coord1 = (float)(n >> 6) * 0.03125f - 1.0f;   // 2*h/H - 1
        float m0 = coord0 + o0 * 0.03125f - 0.015625f;      // + 2*off/W - 1/W
        float m1 = coord1 + o1 * 0.03125f - 0.015625f;

        float na = -(0.5f * LOG2E) * ca;
        float nb = -LOG2E * cb;
        float nc = -(0.5f * LOG2E) * cc;

        params4[pix * 2 + 0] = make_float4(m0, m1, na, nb);
        params4[pix * 2 + 1] = make_float4(nc, r, g, bl);
    }
}

// ---------------------------------------------------------------------------
// Kernel 2: fused render + reduce. Block = (b, ptile of 32 pixels), 1024 thr.
// All 4096 Gaussians of batch b staged in LDS (padded: stride 129 float4/seg).
// Wave w owns pixel-pair (2w, 2w+1) of the tile; lane l integrates Gaussians
// [l*64, l*64+64) for both pixels (dy-terms shared). Full-wave 6-step
// shfl_xor butterfly reduce; lane 0 writes both pixels.
// tt_i = dx_i*(na*dx_i + nb*dy) + nc*dy^2 ; alpha = exp2(tt) gated on tt<=0.
// ---------------------------------------------------------------------------
__global__ __launch_bounds__(1024) void render_kernel(
        const float4* __restrict__ params4,
        float* __restrict__ out) {
    extern __shared__ float4 lp[];   // 64 segs * 129 float4 = 132096 B
    int t = threadIdx.x;
    int bi = blockIdx.x;
    int ptile = bi & 127;            // 32-pixel tile
    int b     = bi >> 7;

    // stage: 8192 float4s; seg = Gaussian>>6, j = Gaussian&63
    const float4* src = params4 + b * (NPIX * 2);
    #pragma unroll
    for (int i = 0; i < 8; ++i) {
        int idx  = t + i * 1024;     // 0..8191
        int nn   = idx >> 1;
        int half = idx & 1;
        int seg  = nn >> 6;
        int j    = nn & 63;
        lp[seg * SEG_STRIDE4 + j * 2 + half] = src[idx];
    }
    __syncthreads();

    int lane = t & 63;
    int wave = t >> 6;               // 0..15
    int p0 = ptile * 32 + wave * 2;  // even column
    int p1 = p0 + 1;

    float px0 = (float)(p0 & 63) * 0.03125f - 1.0f;
    float px1 = px0 + 0.03125f;
    float py  = (float)(p0 >> 6) * 0.03125f - 1.0f;

    const float4* seg_base = lp + lane * SEG_STRIDE4;
    float ar0 = 0.f, ag0 = 0.f, ab0 = 0.f;
    float ar1 = 0.f, ag1 = 0.f, ab1 = 0.f;
    #pragma unroll 8
    for (int j = 0; j < RSEGLEN; ++j) {
        float4 q0 = seg_base[2 * j];     // {m0, m1, na, nb}
        float4 q1 = seg_base[2 * j + 1]; // {nc, r, g, b}
        float dy = py - q0.y;
        float v  = q0.w * dy;            // nb*dy (shared)
        float u  = (q1.x * dy) * dy;     // nc*dy^2 (shared)
        float dx0 = px0 - q0.x;
        float dx1 = dx0 + 0.03125f;
        float tt0 = fmaf(dx0, fmaf(q0.z, dx0, v), u);
        float tt1 = fmaf(dx1, fmaf(q0.z, dx1, v), u);
        float a0 = (tt0 <= 0.0f) ? __builtin_amdgcn_exp2f(tt0) : 0.0f;
        float a1 = (tt1 <= 0.0f) ? __builtin_amdgcn_exp2f(tt1) : 0.0f;
        ar0 = fmaf(a0, q1.y, ar0);
        ag0 = fmaf(a0, q1.z, ag0);
        ab0 = fmaf(a0, q1.w, ab0);
        ar1 = fmaf(a1, q1.y, ar1);
        ag1 = fmaf(a1, q1.z, ag1);
        ab1 = fmaf(a1, q1.w, ab1);
    }

    // full-wave butterfly reduce (all 64 lanes -> total in every lane)
    #define GSUM(v) { v += __shfl_xor(v, 1); v += __shfl_xor(v, 2); \
                      v += __shfl_xor(v, 4); v += __shfl_xor(v, 8); \
                      v += __shfl_xor(v, 16); v += __shfl_xor(v, 32); }
    GSUM(ar0) GSUM(ag0) GSUM(ab0) GSUM(ar1) GSUM(ag1) GSUM(ab1)
    #undef GSUM

    if (lane == 0) {
        ar0 = fminf(fmaxf(ar0, 0.0f), 1.0f);
        ag0 = fminf(fmaxf(ag0, 0.0f), 1.0f);
        ab0 = fminf(fmaxf(ab0, 0.0f), 1.0f);
        ar1 = fminf(fmaxf(ar1, 0.0f), 1.0f);
        ag1 = fminf(fmaxf(ag1, 0.0f), 1.0f);
        ab1 = fminf(fmaxf(ab1, 0.0f), 1.0f);
        out[(b * 3 + 0) * NPIX + p0] = ar0;
        out[(b * 3 + 1) * NPIX + p0] = ag0;
        out[(b * 3 + 2) * NPIX + p0] = ab0;
        out[(b * 3 + 0) * NPIX + p1] = ar1;
        out[(b * 3 + 1) * NPIX + p1] = ag1;
        out[(b * 3 + 2) * NPIX + p1] = ab1;
    }
}

// ---------------------------------------------------------------------------
extern "C" void kernel_launch(void* const* d_in, const int* in_sizes, int n_in,
                              void* d_out, int out_size, void* d_ws, size_t ws_size,
                              hipStream_t stream) {
    const float* inp    = (const float*)d_in[0];  // (2,3,64,64)
    const float* enc_w  = (const float*)d_in[1];  // (64,3,3,3)
    const float* enc_b  = (const float*)d_in[2];  // (64,)
    const float* head_w = (const float*)d_in[3];  // (36,64)
    const float* head_b = (const float*)d_in[4];  // (36,)
    float* out = (float*)d_out;                   // (2,3,64,64)

    float4* params4 = (float4*)d_ws;              // BN*2 float4 = 256 KB

    params_kernel<<<128, 256, 0, stream>>>(inp, enc_w, enc_b,
                                           head_w, head_b, params4);
    size_t shmem = (size_t)RSEG * SEG_STRIDE4 * sizeof(float4);  // 132096 B
    render_kernel<<<BATCH * (NPIX / 32), 1024, shmem, stream>>>(params4, out);
}